// Round 8
// baseline (178.309 us; speedup 1.0000x reference)
//
#include <hip/hip_runtime.h>
#include <hip/hip_bf16.h>

typedef short bf16x8 __attribute__((ext_vector_type(8)));
typedef float f32x4 __attribute__((ext_vector_type(4)));

constexpr int CN = 256, NV = 4096, KTOP = 512;

static __device__ __forceinline__ unsigned short f2bf(float f) {
  __hip_bfloat16 h = __float2bfloat16(f);
  return *(unsigned short*)&h;
}
static __device__ __forceinline__ unsigned pack2(float a, float b) {
  return (unsigned)f2bf(a) | ((unsigned)f2bf(b) << 16);
}
static __device__ __forceinline__ float bf2f(unsigned short u) {
  return __uint_as_float(((unsigned)u) << 16);
}
// truncated-bf16 pack via v_perm_b32: dst = {b[31:16], a[31:16]}  (1 VALU)
static __device__ __forceinline__ unsigned packtrunc(float a, float b) {
  return __builtin_amdgcn_perm(__float_as_uint(b), __float_as_uint(a), 0x07060302u);
}

// ---------------------------------------------------------------- L1: transpose-cast + channel-reduce + weight-prep
// z = 0,1: x_kv batches -> xkv_t ; z = 2,3: x_q batches -> xq_t  (float4 loads)
// z = 4: channel mean/max, 4 columns/thread via float4 (per-column order unchanged)
// z = 5..9: weight prep roles 0..4 (only bx<4 && by<4 active), float4 loads
__global__ void __launch_bounds__(256) k_stage1(const float* __restrict__ xkv,
                                                const float* __restrict__ xq,
                                                const float* __restrict__ wkv,
                                                const float* __restrict__ wq,
                                                const float* __restrict__ wproj,
                                                const float* __restrict__ wpw,
                                                unsigned short* __restrict__ xkv_t,
                                                unsigned short* __restrict__ xq_t,
                                                float* __restrict__ avgmx,
                                                unsigned short* __restrict__ wv_t,
                                                unsigned short* __restrict__ wq_t,
                                                unsigned short* __restrict__ wcat,
                                                unsigned short* __restrict__ wk_t) {
  __shared__ float tile[64 * 68];
  int z = blockIdx.z;
  int t = threadIdx.x;
  if (z == 4) {  // channel mean/max role: 128 n per block, float4 lanes
    __shared__ float4 ssum4[256], smax4[256];
    int blk = blockIdx.y * 64 + blockIdx.x;
    if (blk >= 64) return;
    int b = blk >> 5, n0r = (blk & 31) * 128;
    int cg = t >> 5, nl = t & 31;
    int n = n0r + nl * 4;
    const float* p = xkv + (size_t)b * CN * NV + (size_t)cg * 32 * NV + n;
    float4 s4 = make_float4(0.f, 0.f, 0.f, 0.f);
    float4 m4 = make_float4(-1e30f, -1e30f, -1e30f, -1e30f);
    for (int i = 0; i < 32; ++i) {
      float4 v = *(const float4*)&p[(size_t)i * NV];
      s4.x += v.x; s4.y += v.y; s4.z += v.z; s4.w += v.w;
      m4.x = fmaxf(m4.x, v.x); m4.y = fmaxf(m4.y, v.y);
      m4.z = fmaxf(m4.z, v.z); m4.w = fmaxf(m4.w, v.w);
    }
    ssum4[t] = s4; smax4[t] = m4;
    __syncthreads();
    if (cg == 0) {
      for (int g = 1; g < 8; ++g) {
        float4 o = ssum4[g * 32 + nl], x = smax4[g * 32 + nl];
        s4.x += o.x; s4.y += o.y; s4.z += o.z; s4.w += o.w;
        m4.x = fmaxf(m4.x, x.x); m4.y = fmaxf(m4.y, x.y);
        m4.z = fmaxf(m4.z, x.z); m4.w = fmaxf(m4.w, x.w);
      }
      float4 a4 = make_float4(s4.x * (1.0f / 256.0f), s4.y * (1.0f / 256.0f),
                              s4.z * (1.0f / 256.0f), s4.w * (1.0f / 256.0f));
      *(float4*)&avgmx[(size_t)(b * 2 + 0) * NV + n] = a4;
      *(float4*)&avgmx[(size_t)(b * 2 + 1) * NV + n] = m4;
    }
    return;
  }
  if (z >= 5) {  // weight-prep roles
    if (blockIdx.x >= 4 || blockIdx.y >= 4) return;
    int role = z - 5;
    int j0 = blockIdx.x * 64, c0 = blockIdx.y * 64;
    if (role == 3) {  // wpw (j,c) straight cast into wcat cols 256..512
      int j = t >> 2, part = t & 3;
      const float* s = &wpw[(size_t)(j0 + j) * 256 + c0 + part * 16];
      unsigned w[8];
#pragma unroll
      for (int k = 0; k < 8; ++k) w[k] = pack2(s[2 * k], s[2 * k + 1]);
      uint4* p = (uint4*)&wcat[(size_t)(j0 + j) * 512 + 256 + c0 + part * 16];
      p[0] = make_uint4(w[0], w[1], w[2], w[3]);
      p[1] = make_uint4(w[4], w[5], w[6], w[7]);
      return;
    }
    const float* src; int srcLD, srcOff; unsigned short* dst; int dstLD;
    if (role == 0)      { src = wkv;   srcLD = 512; srcOff = 256; dst = wv_t; dstLD = 256; }
    else if (role == 1) { src = wq;    srcLD = 256; srcOff = 0;   dst = wq_t; dstLD = 256; }
    else if (role == 4) { src = wkv;   srcLD = 512; srcOff = 0;   dst = wk_t; dstLD = 256; }
    else                { src = wproj; srcLD = 256; srcOff = 0;   dst = wcat; dstLD = 512; }
#pragma unroll
    for (int i = 0; i < 4; ++i) {
      int id = i * 256 + t, c = id >> 4, j4 = (id & 15) * 4;
      *(float4*)&tile[c * 68 + j4] =
          *(const float4*)&src[(size_t)(c0 + c) * srcLD + srcOff + j0 + j4];
    }
    __syncthreads();
    int j = t & 63, part = t >> 6;
    unsigned w[8];
#pragma unroll
    for (int k = 0; k < 8; ++k)
      w[k] = pack2(tile[(part * 16 + 2 * k) * 68 + j], tile[(part * 16 + 2 * k + 1) * 68 + j]);
    uint4* p = (uint4*)&dst[(size_t)(j0 + j) * dstLD + c0 + part * 16];
    p[0] = make_uint4(w[0], w[1], w[2], w[3]);
    p[1] = make_uint4(w[4], w[5], w[6], w[7]);
    return;
  }
  // transpose-cast roles: float4 loads (16B/lane), LDS stride 68 keeps stores aligned
  int b = z & 1;
  const float* s = (z < 2 ? xkv : xq) + (size_t)b * CN * NV;
  unsigned short* d = (z < 2 ? xkv_t : xq_t) + (size_t)b * NV * 256;
  int c0 = blockIdx.y * 64, n0 = blockIdx.x * 64;
#pragma unroll
  for (int i = 0; i < 4; ++i) {
    int id = i * 256 + t, c = id >> 4, nq = (id & 15) * 4;
    *(float4*)&tile[c * 68 + nq] = *(const float4*)&s[(size_t)(c0 + c) * NV + n0 + nq];
  }
  __syncthreads();
  int n = t & 63, part = t >> 6;
  unsigned w[8];
#pragma unroll
  for (int k = 0; k < 8; ++k)
    w[k] = pack2(tile[(part * 16 + 2 * k) * 68 + n], tile[(part * 16 + 2 * k + 1) * 68 + n]);
  uint4* p = (uint4*)&d[(size_t)(n0 + n) * 256 + c0 + part * 16];
  p[0] = make_uint4(w[0], w[1], w[2], w[3]);
  p[1] = make_uint4(w[4], w[5], w[6], w[7]);
}

// ---------------------------------------------------------------- L2: fused VK+Q projection (MFMA) + spa conv
// round-18: z = 0,1 -> VK-FUSED role (stage xkv_t B-tile ONCE, run both wv and
// wk against it: -33% staging traffic vs separate V/K roles, same per-output
// accumulation order -> bitwise identical). z = 2,3 -> Q role. z = 4 -> spa.
__global__ void __launch_bounds__(256) k_stage2(const unsigned short* __restrict__ xkv_t,
                                                const unsigned short* __restrict__ xq_t,
                                                const unsigned short* __restrict__ wv_t,
                                                const unsigned short* __restrict__ wq_t,
                                                const unsigned short* __restrict__ wk_t,
                                                const float* __restrict__ bkv,
                                                const float* __restrict__ bq,
                                                const float* __restrict__ avgmx,
                                                const float* __restrict__ wspa,
                                                unsigned short* __restrict__ v_nc,
                                                unsigned short* __restrict__ qh,
                                                unsigned short* __restrict__ k_nc,
                                                float* __restrict__ scores) {
  __shared__ alignas(16) char smem[35520];   // max(VK 20480, Q 15360, spa 35512)
  int z = blockIdx.z;
  int t = threadIdx.x;
  if (z == 4) {  // ---- spa role
    int id = blockIdx.y * 32 + blockIdx.x;
    if (id >= 64) return;
    float* vol = (float*)smem;
    float* ws = (float*)(smem + 32768);
    int b = id >> 5, chunk = id & 31;
    for (int i = t; i < 8192; i += 256) vol[i] = avgmx[b * 8192 + i];
    for (int i = t; i < 686; i += 256) ws[i] = wspa[i];
    __syncthreads();
    int ci = t & 1;
    int n = chunk * 128 + (t >> 1);
    int d = n >> 8, h = (n >> 4) & 15, w = n & 15;
    const float* vb = vol + ci * 4096;
    const float* wb = ws + ci * 343;
    float acc = 0.f;
    for (int kd = 0; kd < 7; ++kd) {
      int zd = d - 3 + kd; if ((unsigned)zd >= 16u) continue;
      for (int kh = 0; kh < 7; ++kh) {
        int zh = h - 3 + kh; if ((unsigned)zh >= 16u) continue;
        const float* row = vb + zd * 256 + zh * 16;
        const float* wr = wb + kd * 49 + kh * 7;
#pragma unroll
        for (int kw = 0; kw < 7; ++kw) {
          int zw = w - 3 + kw;
          if ((unsigned)zw < 16u) acc += row[zw] * wr[kw];
        }
      }
    }
    acc += __shfl_xor(acc, 1);
    if (ci == 0) scores[b * NV + n] = 1.0f / (1.0f + expf(-acc));
    return;
  }
  const float kscale = 0.35355339059327373f * 1.4426950408889634f;  // 1/sqrt(8)*log2(e)
  int wave = t >> 6, lane = t & 63;
  int l15 = lane & 15, q = lane >> 4, q8 = q * 8;
  int wj = (wave >> 1) * 32, wn = (wave & 1) * 64;
  int n0 = blockIdx.x * 128, j0 = blockIdx.y * 64;
  int arA = t >> 2, ahA = t & 3;
  int brB = t >> 1, bhB = t & 1;
  if (z < 2) {  // ---- VK-fused role: one B staging, two A tiles, two outputs
    int b = z;
    unsigned short* Avls = (unsigned short*)smem;       // 64 x 40
    unsigned short* Akls = Avls + 64 * 40;              // 64 x 40
    unsigned short* Bls  = Akls + 64 * 40;              // 128 x 40
    const unsigned short* B = xkv_t + (size_t)b * NV * 256;
    f32x4 accv[2][4] = {}, acck[2][4] = {};
    for (int c0 = 0; c0 < 256; c0 += 32) {
      __syncthreads();
      *(uint4*)&Avls[arA * 40 + ahA * 8] =
          *(const uint4*)&wv_t[(size_t)(j0 + arA) * 256 + c0 + ahA * 8];
      *(uint4*)&Akls[arA * 40 + ahA * 8] =
          *(const uint4*)&wk_t[(size_t)(j0 + arA) * 256 + c0 + ahA * 8];
      const unsigned short* sb = &B[(size_t)(n0 + brB) * 256 + c0 + bhB * 16];
      *(uint4*)&Bls[brB * 40 + bhB * 16]     = *(const uint4*)&sb[0];
      *(uint4*)&Bls[brB * 40 + bhB * 16 + 8] = *(const uint4*)&sb[8];
      __syncthreads();
      bf16x8 afv[2], afk[2], bf[4];
#pragma unroll
      for (int mt = 0; mt < 2; ++mt) {
        afv[mt] = *(const bf16x8*)&Avls[(wj + mt * 16 + l15) * 40 + q8];
        afk[mt] = *(const bf16x8*)&Akls[(wj + mt * 16 + l15) * 40 + q8];
      }
#pragma unroll
      for (int nt = 0; nt < 4; ++nt)
        bf[nt] = *(const bf16x8*)&Bls[(wn + nt * 16 + l15) * 40 + q8];
#pragma unroll
      for (int mt = 0; mt < 2; ++mt)
#pragma unroll
        for (int nt = 0; nt < 4; ++nt) {
          accv[mt][nt] = __builtin_amdgcn_mfma_f32_16x16x32_bf16(afv[mt], bf[nt], accv[mt][nt], 0, 0, 0);
          acck[mt][nt] = __builtin_amdgcn_mfma_f32_16x16x32_bf16(afk[mt], bf[nt], acck[mt][nt], 0, 0, 0);
        }
    }
#pragma unroll
    for (int mt = 0; mt < 2; ++mt) {
      int jb = j0 + wj + mt * 16 + q * 4;
      float4 bv = *(const float4*)&bkv[256 + jb];
      float4 bk = *(const float4*)&bkv[jb];
#pragma unroll
      for (int nt = 0; nt < 4; ++nt) {
        int n = n0 + wn + nt * 16 + l15;
        *(uint2*)&v_nc[((size_t)b * NV + n) * 256 + jb] =
            make_uint2(pack2(accv[mt][nt][0] + bv.x, accv[mt][nt][1] + bv.y),
                       pack2(accv[mt][nt][2] + bv.z, accv[mt][nt][3] + bv.w));
        *(uint2*)&k_nc[((size_t)b * NV + n) * 256 + jb] =
            make_uint2(pack2(acck[mt][nt][0] + bk.x, acck[mt][nt][1] + bk.y),
                       pack2(acck[mt][nt][2] + bk.z, acck[mt][nt][3] + bk.w));
      }
    }
    return;
  }
  // ---- Q role (pre-scaled by kscale*log2e)
  int b = z - 2;
  unsigned short* Als = (unsigned short*)smem;     // 64 x 40
  unsigned short* Bls = Als + 64 * 40;             // 128 x 40
  const unsigned short* B = xq_t + (size_t)b * NV * 256;
  f32x4 acc[2][4] = {};
  for (int c0 = 0; c0 < 256; c0 += 32) {
    __syncthreads();
    *(uint4*)&Als[arA * 40 + ahA * 8] =
        *(const uint4*)&wq_t[(size_t)(j0 + arA) * 256 + c0 + ahA * 8];
    const unsigned short* sb = &B[(size_t)(n0 + brB) * 256 + c0 + bhB * 16];
    *(uint4*)&Bls[brB * 40 + bhB * 16]     = *(const uint4*)&sb[0];
    *(uint4*)&Bls[brB * 40 + bhB * 16 + 8] = *(const uint4*)&sb[8];
    __syncthreads();
    bf16x8 af[2], bf[4];
#pragma unroll
    for (int mt = 0; mt < 2; ++mt)
      af[mt] = *(const bf16x8*)&Als[(wj + mt * 16 + l15) * 40 + q8];
#pragma unroll
    for (int nt = 0; nt < 4; ++nt)
      bf[nt] = *(const bf16x8*)&Bls[(wn + nt * 16 + l15) * 40 + q8];
#pragma unroll
    for (int mt = 0; mt < 2; ++mt)
#pragma unroll
      for (int nt = 0; nt < 4; ++nt)
        acc[mt][nt] = __builtin_amdgcn_mfma_f32_16x16x32_bf16(af[mt], bf[nt], acc[mt][nt], 0, 0, 0);
  }
#pragma unroll
  for (int mt = 0; mt < 2; ++mt) {
    int jb = j0 + wj + mt * 16 + q * 4;
    float4 b4 = *(const float4*)&bq[jb];
    int h = jb >> 3, d0 = jb & 7;
#pragma unroll
    for (int nt = 0; nt < 4; ++nt) {
      int n = n0 + wn + nt * 16 + l15;
      *(uint2*)&qh[((size_t)(b * 32 + h) * NV + n) * 8 + d0] =
          make_uint2(pack2((acc[mt][nt][0] + b4.x) * kscale, (acc[mt][nt][1] + b4.y) * kscale),
                     pack2((acc[mt][nt][2] + b4.z) * kscale, (acc[mt][nt][3] + b4.w) * kscale));
    }
  }
}

// ---------------------------------------------------------------- L3: depthwise conv + top-512 radix select
// bx < 256: dw role (16 n x 256 c per block, 1024 thr) ; bx == 256: topk for batch z
__global__ void __launch_bounds__(1024) k_stage3(const float* __restrict__ scores,
                                                 int* __restrict__ idx,
                                                 const unsigned short* __restrict__ v_nc,
                                                 const float* __restrict__ wdw,
                                                 const float* __restrict__ bdw,
                                                 unsigned short* __restrict__ aoydw) {
  int b = blockIdx.z;
  int bx = blockIdx.x;
  int tid = threadIdx.x;
  if (bx == 256) {  // ---- topk role (unchanged radix-select, 1024 thr)
    __shared__ unsigned sv[4096];
    __shared__ int sB;
    __shared__ unsigned sSub, scnt;
    __shared__ unsigned hist[256];
    __shared__ int wsum[16];
    for (int t = tid; t < 4096; t += 1024) sv[t] = __float_as_uint(scores[b * NV + t]);
    if (tid == 0) scnt = 0;
    unsigned prefix = 0;
    int r = 512;
    for (int shift = 24; shift >= 0; shift -= 8) {
      if (tid < 256) hist[tid] = 0;
      __syncthreads();
      unsigned maskhi = (shift == 24) ? 0u : (0xFFFFFFFFu << (shift + 8));
      for (int i = 0; i < 4; ++i) {
        unsigned v = sv[tid + i * 1024];
        if ((v & maskhi) == prefix) atomicAdd(&hist[(v >> shift) & 255], 1u);
      }
      __syncthreads();
      if (tid < 64) {
        int lane = tid;
        unsigned h0 = hist[lane * 4 + 0], h1 = hist[lane * 4 + 1];
        unsigned h2 = hist[lane * 4 + 2], h3 = hist[lane * 4 + 3];
        unsigned s = h0 + h1 + h2 + h3;
        for (int off = 1; off < 64; off <<= 1) {
          unsigned y = __shfl_down(s, off);
          if (lane + off < 64) s += y;
        }
        unsigned tail = __shfl_down(s, 1);
        if (lane == 63) tail = 0;
        unsigned s3 = tail + h3, s2 = s3 + h2, s1 = s2 + h1, s0 = s1 + h0;
        unsigned sx[5] = {s0, s1, s2, s3, tail};
#pragma unroll
        for (int i = 0; i < 4; ++i)
          if (sx[i] >= (unsigned)r && sx[i + 1] < (unsigned)r) { sB = lane * 4 + i; sSub = sx[i + 1]; }
      }
      __syncthreads();
      prefix |= ((unsigned)sB) << shift;
      r -= (int)sSub;
      __syncthreads();
    }
    unsigned vstar = prefix;
    for (int i = 0; i < 4; ++i) {
      int t = tid * 4 + i;
      if (sv[t] > vstar) { unsigned p = atomicAdd(&scnt, 1u); idx[b * KTOP + p] = t; }
    }
    __syncthreads();
    int base = (int)scnt;
    int loc = 0;
    for (int i = 0; i < 4; ++i) loc += (sv[tid * 4 + i] == vstar);
    int lane = tid & 63, w = tid >> 6;
    int x = loc;
    for (int off = 1; off < 64; off <<= 1) {
      int y = __shfl_up(x, off);
      if (lane >= off) x += y;
    }
    if (lane == 63) wsum[w] = x;
    __syncthreads();
    int wbase = 0;
    for (int i = 0; i < w; ++i) wbase += wsum[i];
    int excl = wbase + x - loc;
    for (int i = 0; i < 4; ++i) {
      int t = tid * 4 + i;
      if (sv[t] == vstar) {
        if (excl < r) idx[b * KTOP + base + excl] = t;
        ++excl;
      }
    }
    return;
  }
  // ---- dw role: 16 consecutive n x 256 c per block
  int c = tid & 255;
  float wr[27];
#pragma unroll
  for (int i = 0; i < 27; ++i) wr[i] = wdw[c * 27 + i];
  float bias = bdw[c];
  const unsigned short* src = v_nc + (size_t)b * NV * 256 + c;
  unsigned short* dst = aoydw + (size_t)b * NV * 512 + 256 + c;
  int n = bx * 16 + (tid >> 8) * 4;          // 4 consecutive n (same h-row) share taps
  int d = n >> 8, h = (n >> 4) & 15, w = n & 15;
  float a0 = bias, a1 = bias, a2 = bias, a3 = bias;
#pragma unroll
  for (int kd = 0; kd < 3; ++kd) {
    int zd = d - 1 + kd; bool okd = (unsigned)zd < 16u;
#pragma unroll
    for (int kh = 0; kh < 3; ++kh) {
      int zh = h - 1 + kh; bool okh = okd && ((unsigned)zh < 16u);
      int rowb = zd * 256 + zh * 16;
      float v[6];
#pragma unroll
      for (int i = 0; i < 6; ++i) {
        int zw = w - 1 + i;
        bool ok = okh && ((unsigned)zw < 16u);   // wave-uniform mask
        v[i] = ok ? bf2f(src[(size_t)(rowb + zw) * 256]) : 0.f;
      }
      const float* wp = &wr[kd * 9 + kh * 3];
      a0 = fmaf(v[0], wp[0], fmaf(v[1], wp[1], fmaf(v[2], wp[2], a0)));
      a1 = fmaf(v[1], wp[0], fmaf(v[2], wp[1], fmaf(v[3], wp[2], a1)));
      a2 = fmaf(v[2], wp[0], fmaf(v[3], wp[1], fmaf(v[4], wp[2], a2)));
      a3 = fmaf(v[3], wp[0], fmaf(v[4], wp[1], fmaf(v[5], wp[2], a3)));
    }
  }
  dst[(size_t)(n + 0) * 512] = f2bf(a0);
  dst[(size_t)(n + 1) * 512] = f2bf(a1);
  dst[(size_t)(n + 2) * 512] = f2bf(a2);
  dst[(size_t)(n + 3) * 512] = f2bf(a3);
}

// ---------------------------------------------------------------- L4: MFMA flash attention, swapped-QK, self-built V^T in LDS
__global__ void __launch_bounds__(256) k_fattn(const unsigned short* __restrict__ qh,
                                               const unsigned short* __restrict__ k_nc,
                                               const unsigned short* __restrict__ v_nc,
                                               const int* __restrict__ idx,
                                               unsigned short* __restrict__ aoydw) {
  __shared__ int idx_l[512];
  __shared__ unsigned short vt_l[16 * 520];
  int bh = blockIdx.x;
  int b = bh >> 5, h = bh & 31;
  int t = threadIdx.x, wave = t >> 6, lane = t & 63;
  int l15 = lane & 15, quad = lane >> 4;
  // ---- phase A: idx + V^T build (kappa-permuted, [16][520] pad)
  const int* ib = idx + b * KTOP;
  for (int i = t; i < 512; i += 256) idx_l[i] = ib[i];
  for (int i = t; i < 512; i += 256) vt_l[8 * 520 + i] = 0x3F80;   // ones row
  for (int i = t; i < 7 * 520; i += 256) vt_l[9 * 520 + i] = 0;    // zero rows
  for (int kk = t; kk < 512; kk += 256) {
    uint4 v = *(const uint4*)&v_nc[((size_t)b * NV + ib[kk]) * 256 + h * 8];
    unsigned short tmp[8];
    *(uint4*)tmp = v;
    int kc = kk >> 5, ka = kk & 31;
    int s = (ka < 16) ? ((ka >> 2) * 8 + (ka & 3))
                      : (((ka - 16) >> 2) * 8 + (ka & 3) + 4);
    int col = kc * 32 + s;
#pragma unroll
    for (int d = 0; d < 8; ++d) vt_l[d * 520 + col] = tmp[d];
  }
  int n0 = blockIdx.y * 128 + wave * 32;       // 32 queries per wave
  bf16x8 q0 = {}, q1 = {};                     // B-operand: n=query, k=dim (quad 0 only)
  if (quad == 0) {
    q0 = *(const bf16x8*)&qh[((size_t)bh * NV + n0 + l15) * 8];
    q1 = *(const bf16x8*)&qh[((size_t)bh * NV + n0 + 16 + l15) * 8];
  }
  __syncthreads();
  // ---- phase B: attention
  const unsigned short* kbase = k_nc + (size_t)b * NV * 256 + h * 8;
  f32x4 acc0 = {0.f, 0.f, 0.f, 0.f}, acc1 = {0.f, 0.f, 0.f, 0.f};
  bf16x8 kA0 = {}, kA1 = {};                   // A-operand: m=key, k=dim (quad 0 only)
  if (quad == 0) {
    kA0 = *(const bf16x8*)&kbase[(size_t)idx_l[l15] * 256];
    kA1 = *(const bf16x8*)&kbase[(size_t)idx_l[16 + l15] * 256];
  }
  for (int kc = 0; kc < 16; ++kc) {            // 32 keys per iteration
    bf16x8 nA0 = {}, nA1 = {};                 // prefetch next K chunk
    if (quad == 0 && kc < 15) {
      nA0 = *(const bf16x8*)&kbase[(size_t)idx_l[kc * 32 + 32 + l15] * 256];
      nA1 = *(const bf16x8*)&kbase[(size_t)idx_l[kc * 32 + 48 + l15] * 256];
    }
    bf16x8 bV = *(const bf16x8*)&vt_l[l15 * 520 + kc * 32 + quad * 8];
    f32x4 z = {0.f, 0.f, 0.f, 0.f};
    // D: col=query=l15, row=key=quad*4+r  -> P already in PV A-frag layout
    f32x4 s00 = __builtin_amdgcn_mfma_f32_16x16x32_bf16(kA0, q0, z, 0, 0, 0);
    f32x4 s01 = __builtin_amdgcn_mfma_f32_16x16x32_bf16(kA1, q0, z, 0, 0, 0);
    f32x4 s10 = __builtin_amdgcn_mfma_f32_16x16x32_bf16(kA0, q1, z, 0, 0, 0);
    f32x4 s11 = __builtin_amdgcn_mfma_f32_16x16x32_bf16(kA1, q1, z, 0, 0, 0);
    uint4 P0, P1;
    P0.x = packtrunc(__builtin_amdgcn_exp2f(s00[0]), __builtin_amdgcn_exp2f(s00[1]));
    P0.y = packtrunc(__builtin_amdgcn_exp2f(s00[2]), __builtin_amdgcn_exp2f(s00[3]));
    P0.z = packtrunc(__builtin_amdgcn_exp2f(s01[0]), __builtin_amdgcn_exp2f(s01[1]));
    P0.w = packtrunc(__builtin_amdgcn_exp2f(s01[2]), __builtin_amdgcn_exp2f(s01[3]));
    P1.x = packtrunc(__builtin_amdgcn_exp2f(s10[0]), __builtin_amdgcn_exp2f(s10[1]));
    P1.y = packtrunc(__builtin_amdgcn_exp2f(s10[2]), __builtin_amdgcn_exp2f(s10[3]));
    P1.z = packtrunc(__builtin_amdgcn_exp2f(s11[0]), __builtin_amdgcn_exp2f(s11[1]));
    P1.w = packtrunc(__builtin_amdgcn_exp2f(s11[2]), __builtin_amdgcn_exp2f(s11[3]));
    acc0 = __builtin_amdgcn_mfma_f32_16x16x32_bf16(*(bf16x8*)&P0, bV, acc0, 0, 0, 0);
    acc1 = __builtin_amdgcn_mfma_f32_16x16x32_bf16(*(bf16x8*)&P1, bV, acc1, 0, 0, 0);
    kA0 = nA0; kA1 = nA1;
  }
#pragma unroll
  for (int tq = 0; tq < 2; ++tq) {
    f32x4 a = tq ? acc1 : acc0;
#pragma unroll
    for (int r = 0; r < 4; ++r) {
      float se = __shfl(a[r], quad * 16 + 8);  // denominator from ones-row col (l15=8)
      float o = a[r] * (1.0f / se);
      if (l15 < 8) {
        int n = n0 + tq * 16 + quad * 4 + r;
        aoydw[((size_t)b * NV + n) * 512 + h * 8 + l15] = f2bf(o);
      }
    }
  }
}

// ---------------------------------------------------------------- L5: final GEMM K=512, MFMA bf16
__global__ void __launch_bounds__(256) k_final(const unsigned short* __restrict__ aoydw,
                                               const unsigned short* __restrict__ wcat,
                                               const float* __restrict__ bproj,
                                               const float* __restrict__ bpw,
                                               float* __restrict__ out) {
  __shared__ unsigned short Als[64 * 72];
  __shared__ unsigned short Bls[64 * 72];
  int n0 = blockIdx.x * 64, j0 = blockIdx.y * 64, b = blockIdx.z;
  int t = threadIdx.x;
  int wave = t >> 6, lane = t & 63;
  int l15 = lane & 15, q = lane >> 4, q8 = q * 8;
  int wn = (wave & 1) * 32, wjj = (wave >> 1) * 32;
  f32x4 acc[2][2] = {};
  const unsigned short* Abase = aoydw + (size_t)b * NV * 512;
  int ar = t >> 2, aq = t & 3;
  for (int c0 = 0; c0 < 512; c0 += 64) {
    __syncthreads();
    *(uint4*)&Als[ar * 72 + aq * 8] =
        *(const uint4*)&Abase[(size_t)(n0 + ar) * 512 + c0 + aq * 8];
    *(uint4*)&Als[ar * 72 + 32 + aq * 8] =
        *(const uint4*)&Abase[(size_t)(n0 + ar) * 512 + c0 + 32 + aq * 8];
    *(uint4*)&Bls[ar * 72 + aq * 8] =
        *(const uint4*)&wcat[(size_t)(j0 + ar) * 512 + c0 + aq * 8];
    *(uint4*)&Bls[ar * 72 + 32 + aq * 8] =
        *(const uint4*)&wcat[(size_t)(j0 + ar) * 512 + c0 + 32 + aq * 8];
    __syncthreads();
#pragma unroll
    for (int kk = 0; kk < 2; ++kk) {
      bf16x8 af[2], bf[2];
#pragma unroll
      for (int mt = 0; mt < 2; ++mt)
        af[mt] = *(const bf16x8*)&Als[(wn + mt * 16 + l15) * 72 + kk * 32 + q8];
#pragma unroll
      for (int nt = 0; nt < 2; ++nt)
        bf[nt] = *(const bf16x8*)&Bls[(wjj + nt * 16 + l15) * 72 + kk * 32 + q8];
#pragma unroll
      for (int mt = 0; mt < 2; ++mt)
#pragma unroll
        for (int nt = 0; nt < 2; ++nt)
          acc[mt][nt] = __builtin_amdgcn_mfma_f32_16x16x32_bf16(af[mt], bf[nt], acc[mt][nt], 0, 0, 0);
    }
  }
#pragma unroll
  for (int nt = 0; nt < 2; ++nt) {
    int j = j0 + wjj + nt * 16 + l15;
    float bl = bproj[j] + bpw[j];
#pragma unroll
    for (int mt = 0; mt < 2; ++mt) {
      int n = n0 + wn + mt * 16 + q * 4;
      float4 r = make_float4(acc[mt][nt][0] + bl, acc[mt][nt][1] + bl,
                             acc[mt][nt][2] + bl, acc[mt][nt][3] + bl);
      *(float4*)&out[(size_t)(b * 256 + j) * NV + n] = r;
    }
  }
}

// ---------------------------------------------------------------- launch
extern "C" void kernel_launch(void* const* d_in, const int* in_sizes, int n_in,
                              void* d_out, int out_size, void* d_ws, size_t ws_size,
                              hipStream_t stream) {
  const float* x_kv   = (const float*)d_in[0];
  const float* x_q    = (const float*)d_in[1];
  const float* w_spa  = (const float*)d_in[2];
  const float* w_kv   = (const float*)d_in[3];
  const float* b_kv   = (const float*)d_in[4];
  const float* w_q    = (const float*)d_in[5];
  const float* b_q    = (const float*)d_in[6];
  const float* w_proj = (const float*)d_in[7];
  const float* b_proj = (const float*)d_in[8];
  const float* w_dw   = (const float*)d_in[9];
  const float* b_dw   = (const float*)d_in[10];
  const float* w_pw   = (const float*)d_in[11];
  const float* b_pw   = (const float*)d_in[12];
  float* out = (float*)d_out;

  const size_t MB = 1024 * 1024;
  char* ws = (char*)d_ws;
  unsigned short* xkv_t = (unsigned short*)(ws);                 // 4 MB (b,n,c) bf16
  unsigned short* xq_t  = (unsigned short*)(ws + 4 * MB);        // 4 MB
  unsigned short* v_nc  = (unsigned short*)(ws + 8 * MB);        // 4 MB (b,n,c) bf16
  unsigned short* qh    = (unsigned short*)(ws + 12 * MB);       // 4 MB (b,h,n,8) bf16, pre-scaled
  unsigned short* aoydw = (unsigned short*)(ws + 16 * MB);       // 8 MB (b,n,512) bf16
  unsigned short* k_nc  = (unsigned short*)(ws + 24 * MB);       // 4 MB (b,n,c) bf16
  unsigned short* wv_t  = (unsigned short*)(ws + 28 * MB);               // 128 KB
  unsigned short* wq_t  = (unsigned short*)(ws + 28 * MB + 131072);      // 128 KB
  unsigned short* wcat  = (unsigned short*)(ws + 28 * MB + 262144);      // 256 KB
  unsigned short* wk_t  = (unsigned short*)(ws + 28 * MB + 524288);      // 128 KB
  float*          avgmx = (float*)(ws + 29 * MB);                        //  64 KB
  float*          scores= (float*)(ws + 29 * MB + 65536);               //  32 KB
  int*            idx   = (int*)  (ws + 29 * MB + 98304);               //   4 KB

  k_stage1<<<dim3(64, 4, 10), 256, 0, stream>>>(x_kv, x_q, w_kv, w_q, w_proj, w_pw,
                                                xkv_t, xq_t, avgmx, wv_t, wq_t, wcat, wk_t);
  k_stage2<<<dim3(32, 4, 5), 256, 0, stream>>>(xkv_t, xq_t, wv_t, wq_t, wk_t, b_kv, b_q,
                                               avgmx, w_spa, v_nc, qh, k_nc, scores);
  k_stage3<<<dim3(257, 1, 2), 1024, 0, stream>>>(scores, idx, v_nc, w_dw, b_dw, aoydw);
  k_fattn<<<dim3(64, 32), 256, 0, stream>>>(qh, k_nc, v_nc, idx, aoydw);
  k_final<<<dim3(64, 4, 2), 256, 0, stream>>>(aoydw, wcat, b_proj, b_pw, out);
}